// Round 12
// baseline (8658.675 us; speedup 1.0000x reference)
//
#include <hip/hip_runtime.h>
#include <cstdint>

#define TT 512

typedef unsigned short u16;
typedef uint32_t u32;
typedef float  floatx4 __attribute__((ext_vector_type(4)));
typedef short  short8  __attribute__((ext_vector_type(8)));

__device__ __forceinline__ float bf2f(u16 u) {
    union { u32 i; float f; } v; v.i = ((u32)u) << 16; return v.f;
}
__device__ __forceinline__ u16 f2bf(float f) {
    union { float f; u32 i; } v; v.f = f;
    u32 x = v.i;
    return (u16)((x + 0x7fffu + ((x >> 16) & 1u)) >> 16);  // RNE
}
__device__ __forceinline__ float sigm(float x)  { return 1.0f / (1.0f + __expf(-x)); }
__device__ __forceinline__ float tanh_(float x) { return 2.0f / (1.0f + __expf(-2.0f * x)) - 1.0f; }
#define BF(p) (*(const short8*)(p))

// frag layout [G][ww][s][t][lane][8] (elem strides: lane 8, t 512, s 4096, ww 32768, G 262144)
// G: 0=W_hh0 1=W_ih1 2=W_hh1 ; row = (t&3)*256 + (2*ww+(t>>2))*16 + (lane&15) ; col = s*32+(lane>>4)*8+j
__device__ __forceinline__ short8 frag_val(int i, const float* W_hh0, const float* W_ih1,
                                           const float* W_hh1) {
    const int l8 = i & 63;
    const int t8 = (i >> 6) & 7;
    const int s8 = (i >> 9) & 7;
    const int w8 = (i >> 12) & 7;
    const int G  = i >> 15;
    const float* W = (G == 0) ? W_hh0 : (G == 1) ? W_ih1 : W_hh1;
    const int row = (t8 & 3) * 256 + (2 * w8 + (t8 >> 2)) * 16 + (l8 & 15);
    const int col = s8 * 32 + (l8 >> 4) * 8;
    const float* src = W + row * 256 + col;
    short8 v;
#pragma unroll
    for (int j = 0; j < 8; ++j) v[j] = (short)f2bf(src[j]);
    return v;
}

#define MM2(ACC, TT_) { short8 A_ = BF(fs + (TT_) * 512); \
    ACC = __builtin_amdgcn_mfma_f32_16x16x32_bf16(A_, Bh, ACC, 0, 0, 0); \
    ACC = __builtin_amdgcn_mfma_f32_16x16x32_bf16(A_, Bl, ACC, 0, 0, 0); }
#define MM2C(ACC, TT_) { short8 A_ = BF(fs2 + (TT_) * 512); \
    ACC = __builtin_amdgcn_mfma_f32_16x16x32_bf16(A_, Ch, ACC, 0, 0, 0); \
    ACC = __builtin_amdgcn_mfma_f32_16x16x32_bf16(A_, Cl, ACC, 0, 0, 0); }

#define GATE1(AI, AF, AG, AO, R, DBASE, BS, CARR, CI, HHI, HLO, POST) { \
    const int d_ = (DBASE) + 4 * q + (R); \
    float zi_ = AI[R] + BS[0][d_]; \
    float zf_ = AF[R] + BS[1][d_]; \
    float zg_ = AG[R] + BS[2][d_]; \
    float zo_ = AO[R] + BS[3][d_]; \
    float c_  = sigm(zf_) * CARR[CI] + sigm(zi_) * tanh_(zg_); \
    CARR[CI] = c_; \
    float hv_ = sigm(zo_) * tanh_(c_); \
    u16 hb_ = f2bf(hv_); \
    HHI[bq][d_] = (short)hb_; \
    HLO[bq][d_] = (short)f2bf(hv_ - bf2f(hb_)); \
    POST }

#define NOP_
#define OUTP_ part += hv_ * who_s[d_];

// Output is FP32 (r11 telemetry proved the harness decodes fp32; r9 probes P=0
// verified the whole compute chain — the only bug left was the out dtype).
__launch_bounds__(512, 2)
__global__ void lstm_block(const float* __restrict__ latent, const float* __restrict__ W_lh,
                           const float* __restrict__ b_lh,
                           const float* __restrict__ W_hh0,
                           const float* __restrict__ b_ih0, const float* __restrict__ b_hh0,
                           const float* __restrict__ W_ih1, const float* __restrict__ W_hh1,
                           const float* __restrict__ b_ih1, const float* __restrict__ b_hh1,
                           const float* __restrict__ W_ho,  const float* __restrict__ b_ho,
                           short* __restrict__ frag, float* __restrict__ out)
{
    __shared__ __align__(16) short h0hi[16][264], h0lo[16][264];
    __shared__ __align__(16) short h1hi[16][264], h1lo[16][264];
    __shared__ float b0s[4][256], b1s[4][256];
    __shared__ float who_s[256];
    __shared__ float osc[8][16];

    const int tid  = threadIdx.x;
    const int ww   = tid >> 6;
    const int lane = tid & 63;
    const int bq   = lane & 15;
    const int q    = lane >> 4;
    const int bglo = blockIdx.x * 16;

    // phase 0: every block writes the entire frag stream (identical bytes; benign race)
    for (int i = tid; i < 98304; i += 512)
        *(short8*)(frag + (size_t)i * 8) = frag_val(i, W_hh0, W_ih1, W_hh1);

    for (int i = tid; i < 1024; i += 512) {
        b0s[i >> 8][i & 255] = b_ih0[i] + b_hh0[i];
        b1s[i >> 8][i & 255] = b_ih1[i] + b_hh1[i];
    }
    if (tid < 256) who_s[tid] = W_ho[tid];

    // h_init = latent @ W_lh.T + b_lh (fp32 GEMV), split hi/lo into both layers' planes
    {
        const int b = tid >> 5, d0 = (tid & 31) * 8;
        const float* lr = latent + (bglo + b) * 128;
#pragma unroll
        for (int j = 0; j < 8; ++j) {
            const int d = d0 + j;
            const float* wr = W_lh + d * 128;
            float acc = b_lh[d];
            for (int c = 0; c < 128; c += 4) {
                float4 lv = *(const float4*)(lr + c);
                float4 wv = *(const float4*)(wr + c);
                acc += lv.x * wv.x + lv.y * wv.y + lv.z * wv.z + lv.w * wv.w;
            }
            u16 hi = f2bf(acc), lo = f2bf(acc - bf2f(hi));
            h0hi[b][d] = (short)hi; h0lo[b][d] = (short)lo;
            h1hi[b][d] = (short)hi; h1lo[b][d] = (short)lo;
        }
    }
    __syncthreads();   // drains frag stores (vmcnt), LDS visible

    const short* fw = frag + (size_t)ww * 32768 + (size_t)lane * 8;

    float c0[8], c1[8];
#pragma unroll
    for (int i = 0; i < 8; ++i) { c0[i] = 0.0f; c1[i] = 0.0f; }
    const float bho = b_ho[0];

    for (int t = 0; t < TT; ++t) {
        // ---- S1: layer-0 z = W_hh0 @ h0(t)
        floatx4 Ai0 = {0.f,0.f,0.f,0.f}, Af0 = {0.f,0.f,0.f,0.f};
        floatx4 Ag0 = {0.f,0.f,0.f,0.f}, Ao0 = {0.f,0.f,0.f,0.f};
        floatx4 Ai1 = {0.f,0.f,0.f,0.f}, Af1 = {0.f,0.f,0.f,0.f};
        floatx4 Ag1 = {0.f,0.f,0.f,0.f}, Ao1 = {0.f,0.f,0.f,0.f};
#pragma unroll 1
        for (int s = 0; s < 8; ++s) {
            const int hoff = s * 32 + q * 8;
            short8 Bh = BF(&h0hi[bq][hoff]);
            short8 Bl = BF(&h0lo[bq][hoff]);
            const short* fs = fw + s * 4096;                  // G=0
            MM2(Ai0, 0) MM2(Af0, 1) MM2(Ag0, 2) MM2(Ao0, 3)
            MM2(Ai1, 4) MM2(Af1, 5) MM2(Ag1, 6) MM2(Ao1, 7)
        }
        __syncthreads();

        // ---- S2: layer-0 gates; write h0' planes
        GATE1(Ai0, Af0, Ag0, Ao0, 0, (2 * ww) * 16,     b0s, c0, 0, h0hi, h0lo, NOP_)
        GATE1(Ai0, Af0, Ag0, Ao0, 1, (2 * ww) * 16,     b0s, c0, 1, h0hi, h0lo, NOP_)
        GATE1(Ai0, Af0, Ag0, Ao0, 2, (2 * ww) * 16,     b0s, c0, 2, h0hi, h0lo, NOP_)
        GATE1(Ai0, Af0, Ag0, Ao0, 3, (2 * ww) * 16,     b0s, c0, 3, h0hi, h0lo, NOP_)
        GATE1(Ai1, Af1, Ag1, Ao1, 0, (2 * ww + 1) * 16, b0s, c0, 4, h0hi, h0lo, NOP_)
        GATE1(Ai1, Af1, Ag1, Ao1, 1, (2 * ww + 1) * 16, b0s, c0, 5, h0hi, h0lo, NOP_)
        GATE1(Ai1, Af1, Ag1, Ao1, 2, (2 * ww + 1) * 16, b0s, c0, 6, h0hi, h0lo, NOP_)
        GATE1(Ai1, Af1, Ag1, Ao1, 3, (2 * ww + 1) * 16, b0s, c0, 7, h0hi, h0lo, NOP_)
        __syncthreads();

        // ---- S3: layer-1 z = W_ih1 @ h0' + W_hh1 @ h1(t-1)
        floatx4 Ci0 = {0.f,0.f,0.f,0.f}, Cf0 = {0.f,0.f,0.f,0.f};
        floatx4 Cg0 = {0.f,0.f,0.f,0.f}, Co0 = {0.f,0.f,0.f,0.f};
        floatx4 Ci1 = {0.f,0.f,0.f,0.f}, Cf1 = {0.f,0.f,0.f,0.f};
        floatx4 Cg1 = {0.f,0.f,0.f,0.f}, Co1 = {0.f,0.f,0.f,0.f};
#pragma unroll 1
        for (int s = 0; s < 8; ++s) {
            const int hoff = s * 32 + q * 8;
            short8 Bh = BF(&h0hi[bq][hoff]);
            short8 Bl = BF(&h0lo[bq][hoff]);
            short8 Ch = BF(&h1hi[bq][hoff]);
            short8 Cl = BF(&h1lo[bq][hoff]);
            const short* fs  = fw + 262144 + s * 4096;   // G=1
            const short* fs2 = fw + 524288 + s * 4096;   // G=2
            MM2(Ci0, 0) MM2(Cf0, 1) MM2(Cg0, 2) MM2(Co0, 3)
            MM2(Ci1, 4) MM2(Cf1, 5) MM2(Cg1, 6) MM2(Co1, 7)
            MM2C(Ci0, 0) MM2C(Cf0, 1) MM2C(Cg0, 2) MM2C(Co0, 3)
            MM2C(Ci1, 4) MM2C(Cf1, 5) MM2C(Cg1, 6) MM2C(Co1, 7)
        }
        __syncthreads();

        // ---- S4: layer-1 gates; write h1' planes; output partial
        float part = 0.0f;
        GATE1(Ci0, Cf0, Cg0, Co0, 0, (2 * ww) * 16,     b1s, c1, 0, h1hi, h1lo, OUTP_)
        GATE1(Ci0, Cf0, Cg0, Co0, 1, (2 * ww) * 16,     b1s, c1, 1, h1hi, h1lo, OUTP_)
        GATE1(Ci0, Cf0, Cg0, Co0, 2, (2 * ww) * 16,     b1s, c1, 2, h1hi, h1lo, OUTP_)
        GATE1(Ci0, Cf0, Cg0, Co0, 3, (2 * ww) * 16,     b1s, c1, 3, h1hi, h1lo, OUTP_)
        GATE1(Ci1, Cf1, Cg1, Co1, 0, (2 * ww + 1) * 16, b1s, c1, 4, h1hi, h1lo, OUTP_)
        GATE1(Ci1, Cf1, Cg1, Co1, 1, (2 * ww + 1) * 16, b1s, c1, 5, h1hi, h1lo, OUTP_)
        GATE1(Ci1, Cf1, Cg1, Co1, 2, (2 * ww + 1) * 16, b1s, c1, 6, h1hi, h1lo, OUTP_)
        GATE1(Ci1, Cf1, Cg1, Co1, 3, (2 * ww + 1) * 16, b1s, c1, 7, h1hi, h1lo, OUTP_)
        part += __shfl_xor(part, 16, 64);
        part += __shfl_xor(part, 32, 64);
        if (q == 0) osc[ww][bq] = part;
        __syncthreads();
        if (tid < 16) {
            float s_ = 0.0f;
#pragma unroll
            for (int w8 = 0; w8 < 8; ++w8) s_ += osc[w8][tid];
            out[(bglo + tid) * TT + t] = s_ + bho;   // FP32 output
        }
    }
}

extern "C" void kernel_launch(void* const* d_in, const int* in_sizes, int n_in,
                              void* d_out, int out_size, void* d_ws, size_t ws_size,
                              hipStream_t stream)
{
    const float* latent = (const float*)d_in[0];
    const float* W_lh   = (const float*)d_in[1];
    const float* b_lh   = (const float*)d_in[2];
    // d_in[3] = W_ih0: unused (layer-0 inputs are all-zero)
    const float* W_hh0  = (const float*)d_in[4];
    const float* b_ih0  = (const float*)d_in[5];
    const float* b_hh0  = (const float*)d_in[6];
    const float* W_ih1  = (const float*)d_in[7];
    const float* W_hh1  = (const float*)d_in[8];
    const float* b_ih1  = (const float*)d_in[9];
    const float* b_hh1  = (const float*)d_in[10];
    const float* W_ho   = (const float*)d_in[11];
    const float* b_ho   = (const float*)d_in[12];

    short* frag = (short*)d_ws;   // 786432 shorts = 1,572,864 B

    lstm_block<<<dim3(16), dim3(512), 0, stream>>>(latent, W_lh, b_lh,
                                                   W_hh0, b_ih0, b_hh0,
                                                   W_ih1, W_hh1, b_ih1, b_hh1,
                                                   W_ho, b_ho, frag, (float*)d_out);
}

// Round 13
// 8589.910 us; speedup vs baseline: 1.0080x; 1.0080x over previous
//
#include <hip/hip_runtime.h>
#include <cstdint>

#define TT 512

typedef unsigned short u16;
typedef uint32_t u32;
typedef float  floatx4 __attribute__((ext_vector_type(4)));
typedef short  short8  __attribute__((ext_vector_type(8)));

__device__ __forceinline__ float bf2f(u16 u) {
    union { u32 i; float f; } v; v.i = ((u32)u) << 16; return v.f;
}
__device__ __forceinline__ u16 f2bf(float f) {
    union { float f; u32 i; } v; v.f = f;
    u32 x = v.i;
    return (u16)((x + 0x7fffu + ((x >> 16) & 1u)) >> 16);  // RNE
}
__device__ __forceinline__ float sigm(float x)  { return 1.0f / (1.0f + __expf(-x)); }
__device__ __forceinline__ float tanh_(float x) { return 2.0f / (1.0f + __expf(-2.0f * x)) - 1.0f; }
#define BF(p) (*(const short8*)(p))

__device__ __forceinline__ u32 ald32(const u32* p) {
    return __hip_atomic_load(p, __ATOMIC_RELAXED, __HIP_MEMORY_SCOPE_AGENT);
}
__device__ __forceinline__ void ast32(u32* p, u32 v) {
    __hip_atomic_store(p, v, __ATOMIC_RELAXED, __HIP_MEMORY_SCOPE_AGENT);
}
__device__ __forceinline__ float aldf(const float* p) {
    return __hip_atomic_load(p, __ATOMIC_RELAXED, __HIP_MEMORY_SCOPE_AGENT);
}
__device__ __forceinline__ void astf(float* p, float v) {
    __hip_atomic_store(p, v, __ATOMIC_RELAXED, __HIP_MEMORY_SCOPE_AGENT);
}

// group barrier: monotonic counter, release-add / acquire-spin (device scope), finite escape
__device__ __forceinline__ void gbar(u32* c, u32 tgt) {
    __hip_atomic_fetch_add(c, 1u, __ATOMIC_RELEASE, __HIP_MEMORY_SCOPE_AGENT);
    int it = 0;
    while (__hip_atomic_load(c, __ATOMIC_ACQUIRE, __HIP_MEMORY_SCOPE_AGENT) < tgt) {
        __builtin_amdgcn_s_sleep(1);
        if (++it > 30000) break;   // finite-wrong, never hang
    }
}

__global__ void zero_cnt(u32* cnt) { cnt[threadIdx.x] = 0; }   // 512 words

#define MFMA_(A_, B_, ACC) ACC = __builtin_amdgcn_mfma_f32_16x16x32_bf16(A_, B_, ACC, 0, 0, 0)

// S1 one gate: A from G0 frag, B = (Bh,Bl)
#define MS1(ACC, GATE_) { short8 A_ = BF(fs0 + (GATE_) * 4096); \
    MFMA_(A_, Bh, ACC); MFMA_(A_, Bl, ACC); }
// S3 one gate: G1 x h0' + G2 x h1
#define MS3(ACC, GATE_) { short8 A1_ = BF(fs1 + (GATE_) * 4096); \
    MFMA_(A1_, B0h, ACC); MFMA_(A1_, B0l, ACC); \
    short8 A2_ = BF(fs2 + (GATE_) * 4096); \
    MFMA_(A2_, B1h, ACC); MFMA_(A2_, B1l, ACC); }

// layer-0 gate at reg R: publish packed h0' to global exchange plane
#define GATE0(R) { \
    const int d_ = dg16 + 4 * q + (R); \
    float zi_ = Zi[R] + b0s[0][d_], zf_ = Zf[R] + b0s[1][d_]; \
    float zg_ = Zg[R] + b0s[2][d_], zo_ = Zo[R] + b0s[3][d_]; \
    float c_  = sigm(zf_) * c0v[R] + sigm(zi_) * tanh_(zg_); c0v[R] = c_; \
    float hv_ = sigm(zo_) * tanh_(c_); \
    u16 hi_ = f2bf(hv_); u16 lo_ = f2bf(hv_ - bf2f(hi_)); \
    ast32(hx0g + d_ * 16 + bq, ((u32)hi_ << 16) | (u32)lo_); }
// layer-1 gate at reg R: publish h1' + output partial
#define GATE1L(R) { \
    const int d_ = dg16 + 4 * q + (R); \
    float zi_ = Yi[R] + b1s[0][d_], zf_ = Yf[R] + b1s[1][d_]; \
    float zg_ = Yg[R] + b1s[2][d_], zo_ = Yo[R] + b1s[3][d_]; \
    float c_  = sigm(zf_) * c1v[R] + sigm(zi_) * tanh_(zg_); c1v[R] = c_; \
    float hv_ = sigm(zo_) * tanh_(c_); \
    u16 hi_ = f2bf(hv_); u16 lo_ = f2bf(hv_ - bf2f(hi_)); \
    ast32(hx1g + d_ * 16 + bq, ((u32)hi_ << 16) | (u32)lo_); \
    part += hv_ * who_s[d_]; }

// 64 blocks = 16 batch-groups x 4 dim-slices; block owns 64 dims/layer, streams 393 KB/step.
// frag layout [G][dg][gate][s][lane][8]; dg in [0,16) = global dim-16-group.
__launch_bounds__(256, 2)
__global__ void lstm_split(const float* __restrict__ latent, const float* __restrict__ W_lh,
                           const float* __restrict__ b_lh,
                           const float* __restrict__ W_hh0,
                           const float* __restrict__ b_ih0, const float* __restrict__ b_hh0,
                           const float* __restrict__ W_ih1, const float* __restrict__ W_hh1,
                           const float* __restrict__ b_ih1, const float* __restrict__ b_hh1,
                           const float* __restrict__ W_ho,  const float* __restrict__ b_ho,
                           short* __restrict__ frag, u32* __restrict__ hx0, u32* __restrict__ hx1,
                           float* __restrict__ posc, u32* __restrict__ cnt,
                           float* __restrict__ out)
{
    __shared__ __align__(16) short h0hi[16][264], h0lo[16][264];   // full h, all 256 dims
    __shared__ __align__(16) short h1hi[16][264], h1lo[16][264];
    __shared__ float b0s[4][256], b1s[4][256];
    __shared__ float who_s[256];
    __shared__ float osc[4][16];

    const int tid  = threadIdx.x;      // 0..255 (4 waves)
    const int w    = tid >> 6;
    const int lane = tid & 63;
    const int bq   = lane & 15;
    const int q    = lane >> 4;
    const int g    = blockIdx.x & 15;  // batch group
    const int j    = blockIdx.x >> 4;  // dim slice 0..3
    const int dg   = 4 * j + w;        // this wave's global dim-16-group
    const int dg16 = dg * 16;
    const int bglo = g * 16;

    // ---- write own weight slice as MFMA fragments (16 groups share slice j: identical bytes)
    for (int i = tid; i < 24576; i += 256) {
        const int l8 = i & 63, s8 = (i >> 6) & 7, gate8 = (i >> 9) & 3;
        const int dgl = (i >> 11) & 3, G = i >> 13;
        const int dgw = 4 * j + dgl;
        const float* W = (G == 0) ? W_hh0 : (G == 1) ? W_ih1 : W_hh1;
        const float* src = W + (gate8 * 256 + dgw * 16 + (l8 & 15)) * 256
                             + s8 * 32 + (l8 >> 4) * 8;
        short8 v;
#pragma unroll
        for (int jj = 0; jj < 8; ++jj) v[jj] = (short)f2bf(src[jj]);
        *(short8*)(frag + (size_t)(l8 * 8 + s8 * 512 + gate8 * 4096 + dgw * 16384 + G * 262144)) = v;
    }
    for (int i = tid; i < 1024; i += 256) {
        b0s[i >> 8][i & 255] = b_ih0[i] + b_hh0[i];
        b1s[i >> 8][i & 255] = b_ih1[i] + b_hh1[i];
    }
    if (tid < 256) who_s[tid] = W_ho[tid];

    // h_init = latent @ W_lh.T + b_lh (fp32), split hi/lo into both layers' LDS planes
    {
        const int b = tid >> 4, d0 = (tid & 15) * 16;
        const float* lr = latent + (bglo + b) * 128;
#pragma unroll
        for (int jj = 0; jj < 16; ++jj) {
            const int d = d0 + jj;
            const float* wr = W_lh + d * 128;
            float acc = b_lh[d];
            for (int c = 0; c < 128; c += 4) {
                float4 lv = *(const float4*)(lr + c);
                float4 wv = *(const float4*)(wr + c);
                acc += lv.x * wv.x + lv.y * wv.y + lv.z * wv.z + lv.w * wv.w;
            }
            u16 hi = f2bf(acc), lo = f2bf(acc - bf2f(hi));
            h0hi[b][d] = (short)hi; h0lo[b][d] = (short)lo;
            h1hi[b][d] = (short)hi; h1lo[b][d] = (short)lo;
        }
    }
    __syncthreads();   // drains frag stores; LDS visible

    const short* f0 = frag + dg * 16384 + (size_t)lane * 8;   // G0 base for this wave
    const short* f1 = f0 + 262144;                            // G1
    const short* f2 = f0 + 524288;                            // G2
    u32* hx0g = hx0 + g * 4096;
    u32* hx1g = hx1 + g * 4096;
    u32* cA = cnt + g * 32;
    u32* cB = cnt + g * 32 + 16;
    float c0v[4] = {0.f, 0.f, 0.f, 0.f}, c1v[4] = {0.f, 0.f, 0.f, 0.f};
    const float bho = b_ho[0];

    for (int t = 0; t < TT; ++t) {
        // ---- S1: z0 (this wave's 4 gate-tiles, 16 dims) over full h0
        floatx4 Zi = {0.f,0.f,0.f,0.f}, Zf = {0.f,0.f,0.f,0.f};
        floatx4 Zg = {0.f,0.f,0.f,0.f}, Zo = {0.f,0.f,0.f,0.f};
#pragma unroll 1
        for (int s = 0; s < 8; ++s) {
            const int hoff = s * 32 + q * 8;
            short8 Bh = BF(&h0hi[bq][hoff]);
            short8 Bl = BF(&h0lo[bq][hoff]);
            const short* fs0 = f0 + s * 512;
            MS1(Zi, 0) MS1(Zf, 1) MS1(Zg, 2) MS1(Zo, 3)
        }
        // ---- S2: layer-0 gates, publish h0' slice
        GATE0(0) GATE0(1) GATE0(2) GATE0(3)
        __syncthreads();                       // drain all lanes' hx0 stores
        if (tid == 0) gbar(cA, 4u * (u32)(t + 1));
        __syncthreads();
        // ---- read back full h0' into LDS
#pragma unroll
        for (int k = 0; k < 16; ++k) {
            const int idx = tid + 256 * k;     // d = idx>>4, b = idx&15
            u32 v = ald32(hx0g + idx);
            h0hi[idx & 15][idx >> 4] = (short)(v >> 16);
            h0lo[idx & 15][idx >> 4] = (short)(v & 0xFFFFu);
        }
        __syncthreads();
        // ---- S3: z1 = W_ih1 @ h0' + W_hh1 @ h1(t-1)
        floatx4 Yi = {0.f,0.f,0.f,0.f}, Yf = {0.f,0.f,0.f,0.f};
        floatx4 Yg = {0.f,0.f,0.f,0.f}, Yo = {0.f,0.f,0.f,0.f};
#pragma unroll 1
        for (int s = 0; s < 8; ++s) {
            const int hoff = s * 32 + q * 8;
            short8 B0h = BF(&h0hi[bq][hoff]);
            short8 B0l = BF(&h0lo[bq][hoff]);
            short8 B1h = BF(&h1hi[bq][hoff]);
            short8 B1l = BF(&h1lo[bq][hoff]);
            const short* fs1 = f1 + s * 512;
            const short* fs2 = f2 + s * 512;
            MS3(Yi, 0) MS3(Yf, 1) MS3(Yg, 2) MS3(Yo, 3)
        }
        // ---- S4: layer-1 gates, publish h1' slice, output partial
        float part = 0.0f;
        GATE1L(0) GATE1L(1) GATE1L(2) GATE1L(3)
        part += __shfl_xor(part, 16, 64);
        part += __shfl_xor(part, 32, 64);
        if (q == 0) osc[w][bq] = part;
        __syncthreads();                       // osc visible + drain hx1 stores
        if (tid < 16)
            astf(posc + g * 64 + j * 16 + tid,
                 osc[0][tid] + osc[1][tid] + osc[2][tid] + osc[3][tid]);
        __syncthreads();                       // drain posc stores
        if (tid == 0) gbar(cB, 4u * (u32)(t + 1));
        __syncthreads();
        // ---- read back full h1' into LDS; slice 0 assembles the output
#pragma unroll
        for (int k = 0; k < 16; ++k) {
            const int idx = tid + 256 * k;
            u32 v = ald32(hx1g + idx);
            h1hi[idx & 15][idx >> 4] = (short)(v >> 16);
            h1lo[idx & 15][idx >> 4] = (short)(v & 0xFFFFu);
        }
        if (j == 0 && tid < 16) {
            float o = bho;
#pragma unroll
            for (int jj = 0; jj < 4; ++jj) o += aldf(posc + g * 64 + jj * 16 + tid);
            out[(bglo + tid) * TT + t] = o;    // FP32 output
        }
    }
}

extern "C" void kernel_launch(void* const* d_in, const int* in_sizes, int n_in,
                              void* d_out, int out_size, void* d_ws, size_t ws_size,
                              hipStream_t stream)
{
    const float* latent = (const float*)d_in[0];
    const float* W_lh   = (const float*)d_in[1];
    const float* b_lh   = (const float*)d_in[2];
    // d_in[3] = W_ih0: unused (layer-0 inputs are all-zero)
    const float* W_hh0  = (const float*)d_in[4];
    const float* b_ih0  = (const float*)d_in[5];
    const float* b_hh0  = (const float*)d_in[6];
    const float* W_ih1  = (const float*)d_in[7];
    const float* W_hh1  = (const float*)d_in[8];
    const float* b_ih1  = (const float*)d_in[9];
    const float* b_hh1  = (const float*)d_in[10];
    const float* W_ho   = (const float*)d_in[11];
    const float* b_ho   = (const float*)d_in[12];

    char* ws = (char*)d_ws;
    short* frag = (short*)ws;                         // 1,572,864 B
    u32*   hx0  = (u32*)(ws + 1572864);               //   262,144 B
    u32*   hx1  = (u32*)(ws + 1835008);               //   262,144 B
    float* posc = (float*)(ws + 2097152);             //     4,096 B
    u32*   cnt  = (u32*)(ws + 2101248);               //     2,048 B   (total ~2.01 MB)

    zero_cnt<<<dim3(1), dim3(512), 0, stream>>>(cnt);
    lstm_split<<<dim3(64), dim3(256), 0, stream>>>(latent, W_lh, b_lh,
                                                   W_hh0, b_ih0, b_hh0,
                                                   W_ih1, W_hh1, b_ih1, b_hh1,
                                                   W_ho, b_ho,
                                                   frag, hx0, hx1, posc, cnt,
                                                   (float*)d_out);
}

// Round 14
// 7215.382 us; speedup vs baseline: 1.2000x; 1.1905x over previous
//
#include <hip/hip_runtime.h>
#include <cstdint>

#define TT 512

typedef unsigned short u16;
typedef uint32_t u32;
typedef float  floatx4 __attribute__((ext_vector_type(4)));
typedef short  short8  __attribute__((ext_vector_type(8)));

__device__ __forceinline__ float bf2f(u16 u) {
    union { u32 i; float f; } v; v.i = ((u32)u) << 16; return v.f;
}
__device__ __forceinline__ u16 f2bf(float f) {
    union { float f; u32 i; } v; v.f = f;
    u32 x = v.i;
    return (u16)((x + 0x7fffu + ((x >> 16) & 1u)) >> 16);  // RNE
}
__device__ __forceinline__ float sigm(float x)  { return 1.0f / (1.0f + __expf(-x)); }
__device__ __forceinline__ float tanh_(float x) { return 2.0f / (1.0f + __expf(-2.0f * x)) - 1.0f; }
#define BF(p) (*(const short8*)(p))

__device__ __forceinline__ u32 ald32(const u32* p) {
    return __hip_atomic_load(p, __ATOMIC_RELAXED, __HIP_MEMORY_SCOPE_AGENT);
}
__device__ __forceinline__ void ast32(u32* p, u32 v) {
    __hip_atomic_store(p, v, __ATOMIC_RELAXED, __HIP_MEMORY_SCOPE_AGENT);
}
__device__ __forceinline__ float aldf(const float* p) {
    return __hip_atomic_load(p, __ATOMIC_RELAXED, __HIP_MEMORY_SCOPE_AGENT);
}
__device__ __forceinline__ void astf(float* p, float v) {
    __hip_atomic_store(p, v, __ATOMIC_RELAXED, __HIP_MEMORY_SCOPE_AGENT);
}

__global__ void zero_flags(u32* flg) { flg[threadIdx.x] = 0; }   // 128 words

#define MFMA_(A_, B_, ACC) ACC = __builtin_amdgcn_mfma_f32_16x16x32_bf16(A_, B_, ACC, 0, 0, 0)
// L0: A from G0 frag, B = h0 (hi/lo)
#define MS1(ACC, GATE_) { short8 A_ = BF(fs0 + (GATE_) * 4096); \
    MFMA_(A_, Bh, ACC); MFMA_(A_, Bl, ACC); }
// L1: G1 x h0(p) + G2 x h1(p-1)
#define MS3(ACC, GATE_) { short8 A1_ = BF(fs1 + (GATE_) * 4096); \
    MFMA_(A1_, Bh, ACC); MFMA_(A1_, Bl, ACC); \
    short8 A2_ = BF(fs2 + (GATE_) * 4096); \
    MFMA_(A2_, Ch, ACC); MFMA_(A2_, Cl, ACC); }

// layer-0 gate at reg R: update c0, publish packed h0(p+1)
#define GATE0(R) { \
    const int d_ = dg16 + 4 * q + (R); \
    float zi_ = Zi[R] + b0s[0][d_], zf_ = Zf[R] + b0s[1][d_]; \
    float zg_ = Zg[R] + b0s[2][d_], zo_ = Zo[R] + b0s[3][d_]; \
    float c_  = sigm(zf_) * c0v[R] + sigm(zi_) * tanh_(zg_); c0v[R] = c_; \
    float hv_ = sigm(zo_) * tanh_(c_); \
    u16 hi_ = f2bf(hv_); u16 lo_ = f2bf(hv_ - bf2f(hi_)); \
    ast32(hx0w + d_ * 16 + bq, ((u32)hi_ << 16) | (u32)lo_); }
// layer-1 gate at reg R: update c1, publish h1(p), accumulate out partial
#define GATE1L(R) { \
    const int d_ = dg16 + 4 * q + (R); \
    float zi_ = Yi[R] + b1s[0][d_], zf_ = Yf[R] + b1s[1][d_]; \
    float zg_ = Yg[R] + b1s[2][d_], zo_ = Yo[R] + b1s[3][d_]; \
    float c_  = sigm(zf_) * c1v[R] + sigm(zi_) * tanh_(zg_); c1v[R] = c_; \
    float hv_ = sigm(zo_) * tanh_(c_); \
    u16 hi_ = f2bf(hv_); u16 lo_ = f2bf(hv_ - bf2f(hi_)); \
    ast32(hx1w + d_ * 16 + bq, ((u32)hi_ << 16) | (u32)lo_); \
    part += hv_ * who_s[d_]; }

// 128 blocks = 16 groups x 8 dim-slices; blockIdx = j*16+g so a group's slices share
// blockIdx%8 (XCD co-location heuristic; correctness via agent-scope ops regardless).
// Skewed pipeline: phase p runs L0(h0(p)->h0(p+1)) AND L1(x=h0(p),h1(p-1)->h1(p)):
// ONE flag-sync + exchange per phase. Exchange planes double-buffered by phase parity.
__launch_bounds__(256, 2)
__global__ void lstm_skew(const float* __restrict__ latent, const float* __restrict__ W_lh,
                          const float* __restrict__ b_lh,
                          const float* __restrict__ W_hh0,
                          const float* __restrict__ b_ih0, const float* __restrict__ b_hh0,
                          const float* __restrict__ W_ih1, const float* __restrict__ W_hh1,
                          const float* __restrict__ b_ih1, const float* __restrict__ b_hh1,
                          const float* __restrict__ W_ho,  const float* __restrict__ b_ho,
                          short* __restrict__ frag, u32* __restrict__ hx0, u32* __restrict__ hx1,
                          float* __restrict__ posc, u32* __restrict__ flg,
                          float* __restrict__ out)
{
    __shared__ __align__(16) short h0hi[16][264], h0lo[16][264];   // h0(p), full 256 dims
    __shared__ __align__(16) short h1hi[16][264], h1lo[16][264];   // h1(p-1)
    __shared__ float b0s[4][256], b1s[4][256];
    __shared__ float who_s[256];
    __shared__ float osc[2][16];

    const int tid  = threadIdx.x;      // 256 threads, 4 waves
    const int w    = tid >> 6;
    const int lane = tid & 63;
    const int bq   = lane & 15;
    const int q    = lane >> 4;
    const int g    = blockIdx.x & 15;  // batch group
    const int j    = blockIdx.x >> 4;  // dim slice 0..7
    const int bglo = g * 16;

    // ---- stage this slice's weight fragments (16 groups write identical bytes: benign)
    for (int i = tid; i < 12288; i += 256) {
        const int l8 = i & 63, s8 = (i >> 6) & 7, gate8 = (i >> 9) & 3;
        const int dgl = (i >> 11) & 1, G = i >> 12;
        const int dgw = 2 * j + dgl;
        const float* W = (G == 0) ? W_hh0 : (G == 1) ? W_ih1 : W_hh1;
        const float* src = W + (gate8 * 256 + dgw * 16 + (l8 & 15)) * 256
                             + s8 * 32 + (l8 >> 4) * 8;
        short8 v;
#pragma unroll
        for (int jj = 0; jj < 8; ++jj) v[jj] = (short)f2bf(src[jj]);
        *(short8*)(frag + (size_t)(l8 * 8 + s8 * 512 + gate8 * 4096 + dgw * 16384 + G * 262144)) = v;
    }
    for (int i = tid; i < 1024; i += 256) {
        b0s[i >> 8][i & 255] = b_ih0[i] + b_hh0[i];
        b1s[i >> 8][i & 255] = b_ih1[i] + b_hh1[i];
    }
    if (tid < 256) who_s[tid] = W_ho[tid];

    // h_init = latent @ W_lh.T + b_lh (fp32), split hi/lo; h0(0) = h1(-1... init) = h_init
    {
        const int b = tid >> 4, d0 = (tid & 15) * 16;
        const float* lr = latent + (bglo + b) * 128;
#pragma unroll
        for (int jj = 0; jj < 16; ++jj) {
            const int d = d0 + jj;
            const float* wr = W_lh + d * 128;
            float acc = b_lh[d];
            for (int c = 0; c < 128; c += 4) {
                float4 lv = *(const float4*)(lr + c);
                float4 wv = *(const float4*)(wr + c);
                acc += lv.x * wv.x + lv.y * wv.y + lv.z * wv.z + lv.w * wv.w;
            }
            u16 hi = f2bf(acc), lo = f2bf(acc - bf2f(hi));
            h0hi[b][d] = (short)hi; h0lo[b][d] = (short)lo;
            h1hi[b][d] = (short)hi; h1lo[b][d] = (short)lo;
        }
    }
    __syncthreads();   // frag stores drained, LDS visible

    // wave roles: w0,w1 = layer 0 (dim-groups 2j, 2j+1); w2,w3 = layer 1 (same dgs)
    const int dgw   = 2 * j + (w & 1);
    const int dg16  = dgw * 16;
    const short* fb0 = frag + dgw * 16384 + (size_t)lane * 8;              // G0
    const short* fb1 = frag + 262144 + dgw * 16384 + (size_t)lane * 8;     // G1
    const short* fb2 = fb1 + 262144;                                       // G2
    u32* myflag = flg + g * 8 + j;
    float c0v[4] = {0.f, 0.f, 0.f, 0.f}, c1v[4] = {0.f, 0.f, 0.f, 0.f};
    const float bho = b_ho[0];

    for (int p = 0; p <= TT; ++p) {
        const int pb = p & 1;
        u32* hx0w = hx0 + pb * 65536 + g * 4096;
        u32* hx1w = hx1 + pb * 65536 + g * 4096;

        // ---- compute + gates + publish (wave-divergent; barriers outside)
        if (w < 2 && p < TT) {          // layer 0
            floatx4 Zi = {0.f,0.f,0.f,0.f}, Zf = {0.f,0.f,0.f,0.f};
            floatx4 Zg = {0.f,0.f,0.f,0.f}, Zo = {0.f,0.f,0.f,0.f};
#pragma unroll 1
            for (int s = 0; s < 8; ++s) {
                const int hoff = s * 32 + q * 8;
                short8 Bh = BF(&h0hi[bq][hoff]);
                short8 Bl = BF(&h0lo[bq][hoff]);
                const short* fs0 = fb0 + s * 512;
                MS1(Zi, 0) MS1(Zf, 1) MS1(Zg, 2) MS1(Zo, 3)
            }
            GATE0(0) GATE0(1) GATE0(2) GATE0(3)
        }
        if (w >= 2 && p >= 1) {         // layer 1 (x = h0(p), state h1(p-1))
            floatx4 Yi = {0.f,0.f,0.f,0.f}, Yf = {0.f,0.f,0.f,0.f};
            floatx4 Yg = {0.f,0.f,0.f,0.f}, Yo = {0.f,0.f,0.f,0.f};
#pragma unroll 1
            for (int s = 0; s < 8; ++s) {
                const int hoff = s * 32 + q * 8;
                short8 Bh = BF(&h0hi[bq][hoff]);
                short8 Bl = BF(&h0lo[bq][hoff]);
                short8 Ch = BF(&h1hi[bq][hoff]);
                short8 Cl = BF(&h1lo[bq][hoff]);
                const short* fs1 = fb1 + s * 512;
                const short* fs2 = fb2 + s * 512;
                MS3(Yi, 0) MS3(Yf, 1) MS3(Yg, 2) MS3(Yo, 3)
            }
            float part = 0.0f;
            GATE1L(0) GATE1L(1) GATE1L(2) GATE1L(3)
            part += __shfl_xor(part, 16, 64);
            part += __shfl_xor(part, 32, 64);
            if (q == 0) osc[w - 2][bq] = part;
        }
        __syncthreads();                 // hx stores drained; osc visible
        if (p >= 1 && tid < 16)
            astf(posc + pb * 2048 + g * 128 + j * 16 + tid, osc[0][tid] + osc[1][tid]);
        __syncthreads();                 // posc drained
        if (tid == 0)
            __hip_atomic_store(myflag, (u32)(p + 1), __ATOMIC_RELEASE, __HIP_MEMORY_SCOPE_AGENT);
        if (tid < 8) {                   // 8 parallel acquire-spins (no RMW barrier)
            const u32 tgt = (u32)(p + 1);
            int it = 0;
            while (__hip_atomic_load(flg + g * 8 + tid, __ATOMIC_ACQUIRE,
                                     __HIP_MEMORY_SCOPE_AGENT) < tgt) {
                __builtin_amdgcn_s_sleep(1);
                if (++it > 50000) break; // finite-wrong, never hang
            }
        }
        __syncthreads();
        // ---- read back full h0(p+1), h1(p) into LDS
        if (p < TT) {
#pragma unroll
            for (int k = 0; k < 16; ++k) {
                const int idx = tid + 256 * k;         // d = idx>>4, b = idx&15
                u32 v = ald32(hx0w + idx);
                h0hi[idx & 15][idx >> 4] = (short)(v >> 16);
                h0lo[idx & 15][idx >> 4] = (short)(v & 0xFFFFu);
            }
        }
        if (p >= 1) {
#pragma unroll
            for (int k = 0; k < 16; ++k) {
                const int idx = tid + 256 * k;
                u32 v = ald32(hx1w + idx);
                h1hi[idx & 15][idx >> 4] = (short)(v >> 16);
                h1lo[idx & 15][idx >> 4] = (short)(v & 0xFFFFu);
            }
            if (j == 0 && tid < 16) {    // assemble out[t = p-1] from 8 slice partials
                float o = bho;
#pragma unroll
                for (int jj = 0; jj < 8; ++jj)
                    o += aldf(posc + pb * 2048 + g * 128 + jj * 16 + tid);
                out[(bglo + tid) * TT + (p - 1)] = o;
            }
        }
        __syncthreads();                 // LDS h planes ready for next phase
    }
}

extern "C" void kernel_launch(void* const* d_in, const int* in_sizes, int n_in,
                              void* d_out, int out_size, void* d_ws, size_t ws_size,
                              hipStream_t stream)
{
    const float* latent = (const float*)d_in[0];
    const float* W_lh   = (const float*)d_in[1];
    const float* b_lh   = (const float*)d_in[2];
    // d_in[3] = W_ih0: unused (layer-0 inputs are all-zero)
    const float* W_hh0  = (const float*)d_in[4];
    const float* b_ih0  = (const float*)d_in[5];
    const float* b_hh0  = (const float*)d_in[6];
    const float* W_ih1  = (const float*)d_in[7];
    const float* W_hh1  = (const float*)d_in[8];
    const float* b_ih1  = (const float*)d_in[9];
    const float* b_hh1  = (const float*)d_in[10];
    const float* W_ho   = (const float*)d_in[11];
    const float* b_ho   = (const float*)d_in[12];

    char* ws = (char*)d_ws;
    short* frag = (short*)ws;                     // 1,572,864 B
    u32*   hx0  = (u32*)(ws + 1572864);           //   524,288 B (2 parities)
    u32*   hx1  = (u32*)(ws + 2097152);           //   524,288 B
    float* posc = (float*)(ws + 2621440);         //    16,384 B (2 parities)
    u32*   flg  = (u32*)(ws + 2637824);           //       512 B   (total ~2.52 MB)

    zero_flags<<<dim3(1), dim3(128), 0, stream>>>(flg);
    lstm_skew<<<dim3(128), dim3(256), 0, stream>>>(latent, W_lh, b_lh,
                                                   W_hh0, b_ih0, b_hh0,
                                                   W_ih1, W_hh1, b_ih1, b_hh1,
                                                   W_ho, b_ho,
                                                   frag, hx0, hx1, posc, flg,
                                                   (float*)d_out);
}

// Round 15
// 4354.914 us; speedup vs baseline: 1.9883x; 1.6568x over previous
//
#include <hip/hip_runtime.h>
#include <cstdint>

#define TT 512

typedef unsigned short u16;
typedef uint32_t u32;
typedef float  floatx4 __attribute__((ext_vector_type(4)));
typedef short  short8  __attribute__((ext_vector_type(8)));

__device__ __forceinline__ float bf2f(u16 u) {
    union { u32 i; float f; } v; v.i = ((u32)u) << 16; return v.f;
}
__device__ __forceinline__ u16 f2bf(float f) {
    union { float f; u32 i; } v; v.f = f;
    u32 x = v.i;
    return (u16)((x + 0x7fffu + ((x >> 16) & 1u)) >> 16);  // RNE
}
__device__ __forceinline__ float sigm(float x)  { return 1.0f / (1.0f + __expf(-x)); }
__device__ __forceinline__ float tanh_(float x) { return 2.0f / (1.0f + __expf(-2.0f * x)) - 1.0f; }
#define BF(p) (*(const short8*)(p))

__global__ void zero_flags(u32* flg) { flg[threadIdx.x] = 0; }   // 128 words

#define MFMA_(A_, B_, ACC) ACC = __builtin_amdgcn_mfma_f32_16x16x32_bf16(A_, B_, ACC, 0, 0, 0)
#define MS1(ACC, GATE_) { short8 A_ = BF(fs0 + (GATE_) * 4096); \
    MFMA_(A_, Bh, ACC); MFMA_(A_, Bl, ACC); }
#define MS3(ACC, GATE_) { short8 A1_ = BF(fs1 + (GATE_) * 4096); \
    MFMA_(A1_, Bh, ACC); MFMA_(A1_, Bl, ACC); \
    short8 A2_ = BF(fs2 + (GATE_) * 4096); \
    MFMA_(A2_, Ch, ACC); MFMA_(A2_, Cl, ACC); }

// layer-0 gate: update c0, publish packed h0(p+1) with a PLAIN store (pipelined;
// visibility is provided by the release-flag's L2 writeback, not per-store atomics)
#define GATE0(R) { \
    const int d_ = dg16 + 4 * q + (R); \
    float zi_ = Zi[R] + b0s[0][d_], zf_ = Zf[R] + b0s[1][d_]; \
    float zg_ = Zg[R] + b0s[2][d_], zo_ = Zo[R] + b0s[3][d_]; \
    float c_  = sigm(zf_) * c0v[R] + sigm(zi_) * tanh_(zg_); c0v[R] = c_; \
    float hv_ = sigm(zo_) * tanh_(c_); \
    u16 hi_ = f2bf(hv_); u16 lo_ = f2bf(hv_ - bf2f(hi_)); \
    hx0w[d_ * 16 + bq] = ((u32)hi_ << 16) | (u32)lo_; }
#define GATE1L(R) { \
    const int d_ = dg16 + 4 * q + (R); \
    float zi_ = Yi[R] + b1s[0][d_], zf_ = Yf[R] + b1s[1][d_]; \
    float zg_ = Yg[R] + b1s[2][d_], zo_ = Yo[R] + b1s[3][d_]; \
    float c_  = sigm(zf_) * c1v[R] + sigm(zi_) * tanh_(zg_); c1v[R] = c_; \
    float hv_ = sigm(zo_) * tanh_(c_); \
    u16 hi_ = f2bf(hv_); u16 lo_ = f2bf(hv_ - bf2f(hi_)); \
    hx1w[d_ * 16 + bq] = ((u32)hi_ << 16) | (u32)lo_; \
    part += hv_ * who_s[d_]; }

// 128 blocks = 16 groups x 8 dim-slices. Skewed pipeline (one sync/phase).
// Exchange protocol per phase:
//   plain data stores -> __syncthreads (vmcnt drain: data at L2)
//   -> tid0 RELEASE flag store (L2 writeback precedes: data at MALL before flag)
//   reader: ACQUIRE spin (final acquire invalidates L1/L2) -> __syncthreads
//   -> plain uint4 loads (fresh from MALL, fully pipelined).
// r14's 12 us/phase mystery was 32 serialized atomic loads (LLVM never batches atomics).
__launch_bounds__(256, 2)
__global__ void lstm_skew(const float* __restrict__ latent, const float* __restrict__ W_lh,
                          const float* __restrict__ b_lh,
                          const float* __restrict__ W_hh0,
                          const float* __restrict__ b_ih0, const float* __restrict__ b_hh0,
                          const float* __restrict__ W_ih1, const float* __restrict__ W_hh1,
                          const float* __restrict__ b_ih1, const float* __restrict__ b_hh1,
                          const float* __restrict__ W_ho,  const float* __restrict__ b_ho,
                          short* __restrict__ frag, u32* __restrict__ hx0, u32* __restrict__ hx1,
                          float* __restrict__ posc, u32* __restrict__ flg,
                          float* __restrict__ out)
{
    __shared__ __align__(16) short h0hi[16][264], h0lo[16][264];   // h0(p), full 256 dims
    __shared__ __align__(16) short h1hi[16][264], h1lo[16][264];   // h1(p-1)
    __shared__ float b0s[4][256], b1s[4][256];
    __shared__ float who_s[256];
    __shared__ float osc[2][16];

    const int tid  = threadIdx.x;      // 256 threads, 4 waves
    const int w    = tid >> 6;
    const int lane = tid & 63;
    const int bq   = lane & 15;
    const int q    = lane >> 4;
    const int g    = blockIdx.x & 15;  // batch group
    const int j    = blockIdx.x >> 4;  // dim slice 0..7
    const int bglo = g * 16;

    // ---- stage this slice's weight fragments (identical bytes across groups: benign race)
    for (int i = tid; i < 12288; i += 256) {
        const int l8 = i & 63, s8 = (i >> 6) & 7, gate8 = (i >> 9) & 3;
        const int dgl = (i >> 11) & 1, G = i >> 12;
        const int dgw = 2 * j + dgl;
        const float* W = (G == 0) ? W_hh0 : (G == 1) ? W_ih1 : W_hh1;
        const float* src = W + (gate8 * 256 + dgw * 16 + (l8 & 15)) * 256
                             + s8 * 32 + (l8 >> 4) * 8;
        short8 v;
#pragma unroll
        for (int jj = 0; jj < 8; ++jj) v[jj] = (short)f2bf(src[jj]);
        *(short8*)(frag + (size_t)(l8 * 8 + s8 * 512 + gate8 * 4096 + dgw * 16384 + G * 262144)) = v;
    }
    for (int i = tid; i < 1024; i += 256) {
        b0s[i >> 8][i & 255] = b_ih0[i] + b_hh0[i];
        b1s[i >> 8][i & 255] = b_ih1[i] + b_hh1[i];
    }
    if (tid < 256) who_s[tid] = W_ho[tid];

    // h_init = latent @ W_lh.T + b_lh (fp32), split hi/lo
    {
        const int b = tid >> 4, d0 = (tid & 15) * 16;
        const float* lr = latent + (bglo + b) * 128;
#pragma unroll
        for (int jj = 0; jj < 16; ++jj) {
            const int d = d0 + jj;
            const float* wr = W_lh + d * 128;
            float acc = b_lh[d];
            for (int c = 0; c < 128; c += 4) {
                float4 lv = *(const float4*)(lr + c);
                float4 wv = *(const float4*)(wr + c);
                acc += lv.x * wv.x + lv.y * wv.y + lv.z * wv.z + lv.w * wv.w;
            }
            u16 hi = f2bf(acc), lo = f2bf(acc - bf2f(hi));
            h0hi[b][d] = (short)hi; h0lo[b][d] = (short)lo;
            h1hi[b][d] = (short)hi; h1lo[b][d] = (short)lo;
        }
    }
    __syncthreads();

    // wave roles: w0,w1 = layer 0 (dim-groups 2j, 2j+1); w2,w3 = layer 1
    const int dgw   = 2 * j + (w & 1);
    const int dg16  = dgw * 16;
    const short* fb0 = frag + dgw * 16384 + (size_t)lane * 8;
    const short* fb1 = frag + 262144 + dgw * 16384 + (size_t)lane * 8;
    const short* fb2 = fb1 + 262144;
    u32* myflag = flg + g * 8 + j;
    float c0v[4] = {0.f, 0.f, 0.f, 0.f}, c1v[4] = {0.f, 0.f, 0.f, 0.f};
    const float bho = b_ho[0];

    for (int p = 0; p <= TT; ++p) {
        const int pb = p & 1;
        u32* hx0w = hx0 + pb * 65536 + g * 4096;
        u32* hx1w = hx1 + pb * 65536 + g * 4096;

        if (w < 2 && p < TT) {          // layer 0
            floatx4 Zi = {0.f,0.f,0.f,0.f}, Zf = {0.f,0.f,0.f,0.f};
            floatx4 Zg = {0.f,0.f,0.f,0.f}, Zo = {0.f,0.f,0.f,0.f};
#pragma unroll 1
            for (int s = 0; s < 8; ++s) {
                const int hoff = s * 32 + q * 8;
                short8 Bh = BF(&h0hi[bq][hoff]);
                short8 Bl = BF(&h0lo[bq][hoff]);
                const short* fs0 = fb0 + s * 512;
                MS1(Zi, 0) MS1(Zf, 1) MS1(Zg, 2) MS1(Zo, 3)
            }
            GATE0(0) GATE0(1) GATE0(2) GATE0(3)
        }
        if (w >= 2 && p >= 1) {         // layer 1
            floatx4 Yi = {0.f,0.f,0.f,0.f}, Yf = {0.f,0.f,0.f,0.f};
            floatx4 Yg = {0.f,0.f,0.f,0.f}, Yo = {0.f,0.f,0.f,0.f};
#pragma unroll 1
            for (int s = 0; s < 8; ++s) {
                const int hoff = s * 32 + q * 8;
                short8 Bh = BF(&h0hi[bq][hoff]);
                short8 Bl = BF(&h0lo[bq][hoff]);
                short8 Ch = BF(&h1hi[bq][hoff]);
                short8 Cl = BF(&h1lo[bq][hoff]);
                const short* fs1 = fb1 + s * 512;
                const short* fs2 = fb2 + s * 512;
                MS3(Yi, 0) MS3(Yf, 1) MS3(Yg, 2) MS3(Yo, 3)
            }
            float part = 0.0f;
            GATE1L(0) GATE1L(1) GATE1L(2) GATE1L(3)
            part += __shfl_xor(part, 16, 64);
            part += __shfl_xor(part, 32, 64);
            if (q == 0) osc[w - 2][bq] = part;
        }
        __syncthreads();                 // hx stores drained to L2; osc visible
        if (p >= 1 && tid < 16)
            posc[pb * 2048 + g * 128 + j * 16 + tid] = osc[0][tid] + osc[1][tid];
        __syncthreads();                 // posc drained
        if (tid == 0)                    // RELEASE: L2 writeback, then flag -> MALL
            __hip_atomic_store(myflag, (u32)(p + 1), __ATOMIC_RELEASE, __HIP_MEMORY_SCOPE_AGENT);
        if (tid < 8) {                   // ACQUIRE spin; final acquire invalidates L1/L2
            const u32 tgt = (u32)(p + 1);
            int it = 0;
            while (__hip_atomic_load(flg + g * 8 + tid, __ATOMIC_ACQUIRE,
                                     __HIP_MEMORY_SCOPE_AGENT) < tgt) {
                __builtin_amdgcn_s_sleep(1);
                if (++it > 50000) break; // finite-wrong, never hang
            }
        }
        __syncthreads();                 // all waves' loads now execute after the inv
        // ---- plain pipelined readback: h0(p+1), h1(p)
        if (p < TT) {
            const uint4* src4 = (const uint4*)hx0w;
#pragma unroll
            for (int k = 0; k < 4; ++k) {
                const int i4 = tid + 256 * k;        // 0..1023 uint4s
                uint4 v = src4[i4];
                const int d = i4 >> 2, b0 = (i4 & 3) * 4;
                h0hi[b0 + 0][d] = (short)(v.x >> 16); h0lo[b0 + 0][d] = (short)(v.x & 0xFFFFu);
                h0hi[b0 + 1][d] = (short)(v.y >> 16); h0lo[b0 + 1][d] = (short)(v.y & 0xFFFFu);
                h0hi[b0 + 2][d] = (short)(v.z >> 16); h0lo[b0 + 2][d] = (short)(v.z & 0xFFFFu);
                h0hi[b0 + 3][d] = (short)(v.w >> 16); h0lo[b0 + 3][d] = (short)(v.w & 0xFFFFu);
            }
        }
        if (p >= 1) {
            const uint4* src4 = (const uint4*)hx1w;
#pragma unroll
            for (int k = 0; k < 4; ++k) {
                const int i4 = tid + 256 * k;
                uint4 v = src4[i4];
                const int d = i4 >> 2, b0 = (i4 & 3) * 4;
                h1hi[b0 + 0][d] = (short)(v.x >> 16); h1lo[b0 + 0][d] = (short)(v.x & 0xFFFFu);
                h1hi[b0 + 1][d] = (short)(v.y >> 16); h1lo[b0 + 1][d] = (short)(v.y & 0xFFFFu);
                h1hi[b0 + 2][d] = (short)(v.z >> 16); h1lo[b0 + 2][d] = (short)(v.z & 0xFFFFu);
                h1hi[b0 + 3][d] = (short)(v.w >> 16); h1lo[b0 + 3][d] = (short)(v.w & 0xFFFFu);
            }
            if (j == 0 && tid < 16) {    // assemble out[t = p-1]
                float o = bho;
#pragma unroll
                for (int jj = 0; jj < 8; ++jj)
                    o += posc[pb * 2048 + g * 128 + jj * 16 + tid];
                out[(bglo + tid) * TT + (p - 1)] = o;
            }
        }
        __syncthreads();                 // LDS h planes ready for next phase
    }
}

extern "C" void kernel_launch(void* const* d_in, const int* in_sizes, int n_in,
                              void* d_out, int out_size, void* d_ws, size_t ws_size,
                              hipStream_t stream)
{
    const float* latent = (const float*)d_in[0];
    const float* W_lh   = (const float*)d_in[1];
    const float* b_lh   = (const float*)d_in[2];
    // d_in[3] = W_ih0: unused (layer-0 inputs are all-zero)
    const float* W_hh0  = (const float*)d_in[4];
    const float* b_ih0  = (const float*)d_in[5];
    const float* b_hh0  = (const float*)d_in[6];
    const float* W_ih1  = (const float*)d_in[7];
    const float* W_hh1  = (const float*)d_in[8];
    const float* b_ih1  = (const float*)d_in[9];
    const float* b_hh1  = (const float*)d_in[10];
    const float* W_ho   = (const float*)d_in[11];
    const float* b_ho   = (const float*)d_in[12];

    char* ws = (char*)d_ws;
    short* frag = (short*)ws;                     // 1,572,864 B
    u32*   hx0  = (u32*)(ws + 1572864);           //   524,288 B (2 parities)
    u32*   hx1  = (u32*)(ws + 2097152);           //   524,288 B
    float* posc = (float*)(ws + 2621440);         //    16,384 B (2 parities)
    u32*   flg  = (u32*)(ws + 2637824);           //       512 B   (total ~2.52 MB)

    zero_flags<<<dim3(1), dim3(128), 0, stream>>>(flg);
    lstm_skew<<<dim3(128), dim3(256), 0, stream>>>(latent, W_lh, b_lh,
                                                   W_hh0, b_ih0, b_hh0,
                                                   W_ih1, W_hh1, b_ih1, b_hh1,
                                                   W_ho, b_ho,
                                                   frag, hx0, hx1, posc, flg,
                                                   (float*)d_out);
}